// Round 4
// baseline (712.709 us; speedup 1.0000x reference)
//
#include <hip/hip_runtime.h>
#include <hip/hip_bf16.h>

typedef __attribute__((ext_vector_type(8))) __bf16 bf16x8;
typedef __attribute__((ext_vector_type(4))) float floatx4;

constexpr int N_TOK = 4096;   // B*T
constexpr int DDIM  = 1024;
constexpr int FDIM  = 4096;
constexpr int NEXP  = 8;
constexpr int NSLOT = 2 * N_TOK; // 8192 assignments (top-2)
constexpr int MAXT  = 72;        // max M-tiles at BM=128: 8192/128 + 7 = 71

static __device__ __forceinline__ unsigned short f2bf(float f) {
    union { __hip_bfloat16 h; unsigned short u; } v;
    v.h = __float2bfloat16(f);
    return v.u;
}

// async 16B global->LDS DMA. LDS dest = wave-uniform base + lane*16 (m104/m108).
static __device__ __forceinline__ void gl2lds16(const unsigned short* g, unsigned short* l) {
    __builtin_amdgcn_global_load_lds(
        (__attribute__((address_space(1))) void*)g,
        (__attribute__((address_space(3))) void*)l,
        16, 0, 0);
}

// ---------------- x cast (+ counts init) ----------------
__global__ void castX_kernel(const float* __restrict__ src, unsigned short* __restrict__ dst,
                             int* __restrict__ counts) {
    int i = blockIdx.x * 256 + threadIdx.x;
    float4 v = *(const float4*)(src + (size_t)i * 4);
    ushort4 o;
    o.x = f2bf(v.x); o.y = f2bf(v.y); o.z = f2bf(v.z); o.w = f2bf(v.w);
    *(ushort4*)(dst + (size_t)i * 4) = o;
    if (blockIdx.x == 0 && threadIdx.x < NEXP) counts[threadIdx.x] = 0;
}

// ---------------- fused W1+W2 fp32 -> bf16 cast ----------------
__global__ void castW_kernel(const float* __restrict__ W1, const float* __restrict__ W2,
                             unsigned short* __restrict__ w1b, unsigned short* __restrict__ w2b) {
    constexpr int HALF = NEXP * FDIM * DDIM / 4; // float4 groups per tensor
    int i = blockIdx.x * 256 + threadIdx.x;
    const float* s; unsigned short* d; int j;
    if (i < HALF) { s = W1; d = w1b; j = i; }
    else          { s = W2; d = w2b; j = i - HALF; }
    float4 v = *(const float4*)(s + (size_t)j * 4);
    ushort4 o;
    o.x = f2bf(v.x); o.y = f2bf(v.y); o.z = f2bf(v.z); o.w = f2bf(v.w);
    *(ushort4*)(d + (size_t)j * 4) = o;
}

// ---------------- router: logits -> top2 -> weights ----------------
__global__ void router_kernel(const float* __restrict__ x, const float* __restrict__ Wr,
                              int* __restrict__ te, float* __restrict__ tw,
                              int* __restrict__ counts) {
    __shared__ float wr[NEXP * DDIM]; // 32 KB
    const int tid = threadIdx.x;
    for (int i = tid; i < NEXP * DDIM; i += 256) wr[i] = Wr[i];
    __syncthreads();
    const int wave = tid >> 6, lane = tid & 63;
    const int t = blockIdx.x * 4 + wave;

    float xr[16];
    const float* xp = x + (size_t)t * DDIM;
    #pragma unroll
    for (int i = 0; i < 16; i++) xr[i] = xp[lane + 64 * i];

    float logit[NEXP];
    #pragma unroll
    for (int e = 0; e < NEXP; e++) {
        float s = 0.f;
        #pragma unroll
        for (int i = 0; i < 16; i++) s += xr[i] * wr[e * DDIM + lane + 64 * i];
        #pragma unroll
        for (int off = 32; off > 0; off >>= 1) s += __shfl_xor(s, off, 64);
        logit[e] = s;
    }
    if (lane == 0) {
        int i0 = 0; float l0 = logit[0];
        #pragma unroll
        for (int e = 1; e < NEXP; e++) if (logit[e] > l0) { l0 = logit[e]; i0 = e; }
        int i1 = -1; float l1 = -3.0e38f;
        #pragma unroll
        for (int e = 0; e < NEXP; e++) if (e != i0 && logit[e] > l1) { l1 = logit[e]; i1 = e; }
        float p1 = expf(l1 - l0);
        float w0 = 1.f / (1.f + p1);
        float w1 = p1 * w0;
        te[t * 2] = i0; te[t * 2 + 1] = i1;
        tw[t * 2] = w0; tw[t * 2 + 1] = w1;
        atomicAdd(&counts[i0], 1);
        atomicAdd(&counts[i1], 1);
    }
}

// ---------------- fused scan + tile table + scatter (single block) ----------------
__global__ void scan_scatter_kernel(const int* __restrict__ counts,
                                    const int* __restrict__ te, const float* __restrict__ tw,
                                    int* __restrict__ offsets, int* __restrict__ tile_em,
                                    int* __restrict__ ntile,
                                    int* __restrict__ rowid, float* __restrict__ gate,
                                    int* __restrict__ tok2slot) {
    __shared__ int soff[NEXP];
    __shared__ int scur[NEXP];
    const int tid = threadIdx.x;
    if (tid == 0) {
        int acc = 0, nt = 0;
        for (int e = 0; e < NEXP; e++) {
            offsets[e] = acc; soff[e] = acc;
            for (int m0 = 0; m0 < counts[e]; m0 += 128)
                tile_em[nt++] = (e << 16) | (m0 >> 7);
            acc += counts[e];
        }
        offsets[NEXP] = acc;
        ntile[0] = nt;
        for (int i = nt; i < MAXT; i++) tile_em[i] = 0;
    }
    if (tid < NEXP) scur[tid] = 0;
    __syncthreads();
    for (int t = tid; t < N_TOK; t += 256) {
        #pragma unroll
        for (int k = 0; k < 2; k++) {
            int e = te[t * 2 + k];
            int pos = atomicAdd(&scur[e], 1);
            int slot = soff[e] + pos;
            rowid[slot] = t;
            gate[slot] = tw[t * 2 + k];
            tok2slot[t * 2 + k] = slot;
        }
    }
}

// ---------------- grouped GEMM: BK=64, XCD-slab schedule, XOR-swizzled LDS ----------------
// UP:  A = xb gathered rows [cnt x 1024] @ W1^T -> gelu -> H bf16
// DOWN:A = H rows [cnt x 4096] @ W2^T -> gate*  -> Y fp32 per slot
template <int K, bool UP>
__global__ __launch_bounds__(256)
void ffn_gemm(const unsigned short* __restrict__ A,
              const unsigned short* __restrict__ Wb,
              unsigned short* __restrict__ Hout,
              float* __restrict__ Y,
              const int* __restrict__ rowid,
              const float* __restrict__ gate,
              const int* __restrict__ offsets,
              const int* __restrict__ tile_em,
              const int* __restrict__ ntile) {
    constexpr int BM = 128, BN = 128, BK = 64;
    constexpr int NOUT  = UP ? FDIM : DDIM;
    constexpr int NSLAB = (NOUT / BN) / 8;   // n-tiles per XCD: up 4, down 1

    // XCD-slab: blockIdx%8 = XCD (round-robin heuristic); each XCD owns a fixed
    // n-slab and runs M-innermost within it -> B tiles stay hot in that XCD's L2.
    const int id    = blockIdx.x;
    const int xcd   = id & 7;
    const int local = id >> 3;
    const int nloc  = local / MAXT;
    const int bt    = local - nloc * MAXT;
    if (bt >= ntile[0]) return;
    const int em = tile_em[bt];
    const int e  = em >> 16;
    const int m0 = (em & 0xffff) << 7;
    const int n0 = (xcd * NSLAB + nloc) * BN;
    const int seg = offsets[e];
    const int cnt = offsets[e + 1] - seg;

    __shared__ __align__(16) unsigned short As[BM * BK];  // 16 KB
    __shared__ __align__(16) unsigned short Bs[BN * BK];  // 16 KB

    const int tid  = threadIdx.x;
    const int lane = tid & 63;
    const int wave = tid >> 6;

    // --- staging: per wave 32 A rows + 32 B rows, 8 rows per DMA instr ---
    // XOR swizzle: row r stores global 16B-chunk c at LDS column c^(r&7).
    // With the fixed lane->LDS map (lane*16B), lane = rl*8+cs writes column cs
    // of row rl, so it must FETCH global chunk cs^rl.
    const int rl   = lane >> 3;        // row within 8-row group (== row&7)
    const int cg   = (lane & 7) ^ rl;  // global chunk this lane fetches

    const unsigned short* ag[4];
    #pragma unroll
    for (int j = 0; j < 4; j++) {
        int r = wave * 32 + j * 8 + rl;
        int slot = seg + m0 + r;
        if (slot >= NSLOT) slot = NSLOT - 1;  // clamp; write-guarded later
        if (UP) { int t = rowid[slot]; ag[j] = A + (size_t)t * DDIM + cg * 8; }
        else    { ag[j] = A + (size_t)slot * FDIM + cg * 8; }
    }
    const unsigned short* bg[4];
    #pragma unroll
    for (int j = 0; j < 4; j++) {
        int r = wave * 32 + j * 8 + rl;
        bg[j] = Wb + ((size_t)e * NOUT + n0 + r) * K + cg * 8;
    }
    unsigned short* asl[4];
    unsigned short* bsl[4];
    #pragma unroll
    for (int j = 0; j < 4; j++) {
        asl[j] = &As[(wave * 32 + j * 8) * BK] + lane * 8;
        bsl[j] = &Bs[(wave * 32 + j * 8) * BK] + lane * 8;
    }

    const int wm = (wave >> 1) * 64;
    const int wn = (wave & 1) * 64;
    const int frow = lane & 15;
    const int quad = lane >> 4;
    const int f7 = frow & 7;

    floatx4 acc[4][4];
    #pragma unroll
    for (int i = 0; i < 4; i++)
        #pragma unroll
        for (int j = 0; j < 4; j++)
            acc[i][j] = (floatx4){0.f, 0.f, 0.f, 0.f};

    for (int k0 = 0; k0 < K; k0 += BK) {
        __syncthreads();                 // WAR: previous iter's ds_reads done
        #pragma unroll
        for (int j = 0; j < 4; j++) gl2lds16(ag[j], asl[j]);
        #pragma unroll
        for (int j = 0; j < 4; j++) gl2lds16(bg[j], bsl[j]);
        #pragma unroll
        for (int j = 0; j < 4; j++) { ag[j] += BK; bg[j] += BK; }
        __syncthreads();                 // drain DMA

        #pragma unroll
        for (int kk = 0; kk < 2; kk++) {
            bf16x8 av[4], bv[4];
            #pragma unroll
            for (int i = 0; i < 4; i++)
                av[i] = *(const bf16x8*)&As[(wm + i * 16 + frow) * BK + ((kk * 4 + quad) ^ f7) * 8];
            #pragma unroll
            for (int i = 0; i < 4; i++)
                bv[i] = *(const bf16x8*)&Bs[(wn + i * 16 + frow) * BK + ((kk * 4 + quad) ^ f7) * 8];
            #pragma unroll
            for (int mt = 0; mt < 4; mt++)
                #pragma unroll
                for (int nt = 0; nt < 4; nt++)
                    acc[mt][nt] = __builtin_amdgcn_mfma_f32_16x16x32_bf16(av[mt], bv[nt], acc[mt][nt], 0, 0, 0);
        }
    }

    // epilogue: C/D layout col=lane&15, row=quad*4+reg (m89/m91-verified)
    #pragma unroll
    for (int mt = 0; mt < 4; mt++) {
        #pragma unroll
        for (int r = 0; r < 4; r++) {
            int mloc = m0 + wm + mt * 16 + quad * 4 + r;
            if (mloc >= cnt) continue;   // write-guard
            int slot = seg + mloc;
            if (UP) {
                #pragma unroll
                for (int nt = 0; nt < 4; nt++) {
                    int n = n0 + wn + nt * 16 + frow;
                    float v = acc[mt][nt][r];
                    float g = 0.5f * v * (1.0f + erff(v * 0.70710678118654752f)); // exact gelu
                    Hout[(size_t)slot * FDIM + n] = f2bf(g);
                }
            } else {
                float gw = gate[slot];
                #pragma unroll
                for (int nt = 0; nt < 4; nt++) {
                    int n = n0 + wn + nt * 16 + frow;
                    Y[(size_t)slot * DDIM + n] = gw * acc[mt][nt][r];
                }
            }
        }
    }
}

// ---------------- combine: out[t] = Y[slot0(t)] + Y[slot1(t)] ----------------
__global__ void combine_kernel(const float* __restrict__ Y, const int* __restrict__ tok2slot,
                               float* __restrict__ out) {
    int idx = blockIdx.x * 256 + threadIdx.x;
    int t = idx >> 8;
    int c = (idx & 255) * 4;
    int s0 = tok2slot[t * 2], s1 = tok2slot[t * 2 + 1];
    float4 a = *(const float4*)(Y + (size_t)s0 * DDIM + c);
    float4 b = *(const float4*)(Y + (size_t)s1 * DDIM + c);
    *(float4*)(out + (size_t)t * DDIM + c) =
        make_float4(a.x + b.x, a.y + b.y, a.z + b.z, a.w + b.w);
}

extern "C" void kernel_launch(void* const* d_in, const int* in_sizes, int n_in,
                              void* d_out, int out_size, void* d_ws, size_t ws_size,
                              hipStream_t stream) {
    const float* x  = (const float*)d_in[0];
    const float* Wr = (const float*)d_in[1];
    const float* W1 = (const float*)d_in[2];
    const float* W2 = (const float*)d_in[3];
    float* out = (float*)d_out;

    char* ws = (char*)d_ws;
    size_t off = 0;
    auto alloc = [&](size_t bytes) -> char* {
        char* p = ws + off;
        off = (off + bytes + 255) & ~(size_t)255;
        return p;
    };
    unsigned short* xb   = (unsigned short*)alloc((size_t)N_TOK * DDIM * 2);
    unsigned short* H    = (unsigned short*)alloc((size_t)NSLOT * FDIM * 2);
    float* Yb      = (float*)alloc((size_t)NSLOT * DDIM * 4);
    int*   rowid   = (int*)alloc(NSLOT * 4);
    float* gatew   = (float*)alloc(NSLOT * 4);
    int*   te      = (int*)alloc(NSLOT * 4);
    float* tw      = (float*)alloc(NSLOT * 4);
    int*   t2s     = (int*)alloc(NSLOT * 4);
    int*   counts  = (int*)alloc(64);
    int*   offsets = (int*)alloc(64);
    int*   tile_em = (int*)alloc(MAXT * 4);
    int*   ntile   = (int*)alloc(64);
    unsigned short* w1b = (unsigned short*)alloc((size_t)NEXP * FDIM * DDIM * 2);
    unsigned short* w2b = (unsigned short*)alloc((size_t)NEXP * DDIM * FDIM * 2);
    (void)ws_size;

    castX_kernel<<<N_TOK * DDIM / 4 / 256, 256, 0, stream>>>(x, xb, counts);
    castW_kernel<<<2 * NEXP * FDIM * DDIM / 4 / 256, 256, 0, stream>>>(W1, W2, w1b, w2b);
    router_kernel<<<N_TOK / 4, 256, 0, stream>>>(x, Wr, te, tw, counts);
    scan_scatter_kernel<<<1, 256, 0, stream>>>(counts, te, tw, offsets, tile_em, ntile,
                                               rowid, gatew, t2s);
    ffn_gemm<DDIM, true ><<<8 * 4 * MAXT, 256, 0, stream>>>(xb, w1b, H, Yb, rowid, gatew,
                                                            offsets, tile_em, ntile);
    ffn_gemm<FDIM, false><<<8 * 1 * MAXT, 256, 0, stream>>>(H,  w2b, H, Yb, rowid, gatew,
                                                            offsets, tile_em, ntile);
    combine_kernel<<<N_TOK, 256, 0, stream>>>(Yb, t2s, out);
}

// Round 5
// 668.569 us; speedup vs baseline: 1.0660x; 1.0660x over previous
//
#include <hip/hip_runtime.h>
#include <hip/hip_bf16.h>

typedef __attribute__((ext_vector_type(8))) __bf16 bf16x8;
typedef __attribute__((ext_vector_type(4))) float floatx4;

constexpr int N_TOK = 4096;   // B*T
constexpr int DDIM  = 1024;
constexpr int FDIM  = 4096;
constexpr int NEXP  = 8;
constexpr int NSLOT = 2 * N_TOK; // 8192 assignments (top-2)
constexpr int MAXT  = 72;        // max M-tiles at BM=128: 8192/128 + 7 = 71
constexpr int KSPLIT = 2;        // down-GEMM K split
constexpr int NN_UP = FDIM / 128;
constexpr int NN_DN = DDIM / 128;

static __device__ __forceinline__ unsigned short f2bf(float f) {
    union { __hip_bfloat16 h; unsigned short u; } v;
    v.h = __float2bfloat16(f);
    return v.u;
}

// async 16B global->LDS DMA. LDS dest = wave-uniform base + lane*16 (m104/m108).
static __device__ __forceinline__ void gl2lds16(const unsigned short* g, unsigned short* l) {
    __builtin_amdgcn_global_load_lds(
        (__attribute__((address_space(1))) void*)g,
        (__attribute__((address_space(3))) void*)l,
        16, 0, 0);
}

// ---------------- fused W1+W2 fp32 -> bf16 cast (+ counts init) ----------------
__global__ void castW_kernel(const float* __restrict__ W1, const float* __restrict__ W2,
                             unsigned short* __restrict__ w1b, unsigned short* __restrict__ w2b,
                             int* __restrict__ counts) {
    constexpr int HALF = NEXP * FDIM * DDIM / 4; // float4 groups per tensor
    int i = blockIdx.x * 256 + threadIdx.x;
    const float* s; unsigned short* d; int j;
    if (i < HALF) { s = W1; d = w1b; j = i; }
    else          { s = W2; d = w2b; j = i - HALF; }
    float4 v = *(const float4*)(s + (size_t)j * 4);
    ushort4 o;
    o.x = f2bf(v.x); o.y = f2bf(v.y); o.z = f2bf(v.z); o.w = f2bf(v.w);
    *(ushort4*)(d + (size_t)j * 4) = o;
    if (blockIdx.x == 0 && threadIdx.x < NEXP) counts[threadIdx.x] = 0;
}

// ---------------- router: logits -> top2 -> weights; also emits xb ----------------
__global__ void router_kernel(const float* __restrict__ x, const float* __restrict__ Wr,
                              unsigned short* __restrict__ xb,
                              int* __restrict__ te, float* __restrict__ tw,
                              int* __restrict__ counts) {
    __shared__ float wr[NEXP * DDIM]; // 32 KB
    const int tid = threadIdx.x;
    for (int i = tid; i < NEXP * DDIM; i += 256) wr[i] = Wr[i];
    __syncthreads();
    const int wave = tid >> 6, lane = tid & 63;
    const int t = blockIdx.x * 4 + wave;

    float xr[16];
    const float* xp = x + (size_t)t * DDIM;
    #pragma unroll
    for (int i = 0; i < 16; i++) xr[i] = xp[lane + 64 * i];

    // fused x -> bf16 cast (same row already in registers)
    unsigned short* xbp = xb + (size_t)t * DDIM;
    #pragma unroll
    for (int i = 0; i < 16; i++) xbp[lane + 64 * i] = f2bf(xr[i]);

    float logit[NEXP];
    #pragma unroll
    for (int e = 0; e < NEXP; e++) {
        float s = 0.f;
        #pragma unroll
        for (int i = 0; i < 16; i++) s += xr[i] * wr[e * DDIM + lane + 64 * i];
        #pragma unroll
        for (int off = 32; off > 0; off >>= 1) s += __shfl_xor(s, off, 64);
        logit[e] = s;
    }
    if (lane == 0) {
        int i0 = 0; float l0 = logit[0];
        #pragma unroll
        for (int e = 1; e < NEXP; e++) if (logit[e] > l0) { l0 = logit[e]; i0 = e; }
        int i1 = -1; float l1 = -3.0e38f;
        #pragma unroll
        for (int e = 0; e < NEXP; e++) if (e != i0 && logit[e] > l1) { l1 = logit[e]; i1 = e; }
        float p1 = expf(l1 - l0);
        float w0 = 1.f / (1.f + p1);
        float w1 = p1 * w0;
        te[t * 2] = i0; te[t * 2 + 1] = i1;
        tw[t * 2] = w0; tw[t * 2 + 1] = w1;
        atomicAdd(&counts[i0], 1);
        atomicAdd(&counts[i1], 1);
    }
}

// ---------------- fused scan + tile table + scatter (single block) ----------------
__global__ void scan_scatter_kernel(const int* __restrict__ counts,
                                    const int* __restrict__ te, const float* __restrict__ tw,
                                    int* __restrict__ offsets, int* __restrict__ tile_em,
                                    int* __restrict__ ntile,
                                    int* __restrict__ rowid, float* __restrict__ gate,
                                    int* __restrict__ tok2slot) {
    __shared__ int soff[NEXP];
    __shared__ int scur[NEXP];
    const int tid = threadIdx.x;
    if (tid == 0) {
        int acc = 0, nt = 0;
        for (int e = 0; e < NEXP; e++) {
            offsets[e] = acc; soff[e] = acc;
            for (int m0 = 0; m0 < counts[e]; m0 += 128)
                tile_em[nt++] = (e << 16) | (m0 >> 7);
            acc += counts[e];
        }
        offsets[NEXP] = acc;
        ntile[0] = nt;
        for (int i = nt; i < MAXT; i++) tile_em[i] = 0;
    }
    if (tid < NEXP) scur[tid] = 0;
    __syncthreads();
    for (int t = tid; t < N_TOK; t += 256) {
        #pragma unroll
        for (int k = 0; k < 2; k++) {
            int e = te[t * 2 + k];
            int pos = atomicAdd(&scur[e], 1);
            int slot = soff[e] + pos;
            rowid[slot] = t;
            gate[slot] = tw[t * 2 + k];
            tok2slot[t * 2 + k] = slot;
        }
    }
}

// ---------------- grouped GEMM (R2-proven structure; BK=32, n-fastest) ----------------
// UP:  A = xb gathered rows [cnt x 1024] @ W1^T -> gelu -> H bf16
// DOWN:A = H rows [cnt x 4096] @ W2^T (K-split)  -> gate* -> Y fp32 slab per ks
template <bool UP>
__global__ __launch_bounds__(256)
void ffn_gemm(const unsigned short* __restrict__ A,
              const unsigned short* __restrict__ Wb,
              unsigned short* __restrict__ Hout,
              float* __restrict__ Y,
              const int* __restrict__ rowid,
              const float* __restrict__ gate,
              const int* __restrict__ offsets,
              const int* __restrict__ tile_em,
              const int* __restrict__ ntile) {
    constexpr int BM = 128, BN = 128, BK = 32, LDT = 32;
    constexpr int NOUT = UP ? FDIM : DDIM;
    constexpr int KDIM = UP ? DDIM : FDIM;
    constexpr int NN   = UP ? NN_UP : NN_DN;
    constexpr int KLEN = UP ? DDIM : (FDIM / KSPLIT);

    // n fastest (R2-best ordering): consecutive blocks share the A tile.
    const int id = blockIdx.x;
    const int n0 = (id % NN) * BN;
    const int bt = (id / NN) % MAXT;
    const int ks = UP ? 0 : (id / (NN * MAXT));
    if (bt >= ntile[0]) return;
    const int em = tile_em[bt];
    const int e  = em >> 16;
    const int m0 = (em & 0xffff) << 7;
    const int seg = offsets[e];
    const int cnt = offsets[e + 1] - seg;
    const int kbase = ks * KLEN;

    __shared__ __align__(16) unsigned short As[BM * LDT];
    __shared__ __align__(16) unsigned short Bs[BN * LDT];

    const int tid  = threadIdx.x;
    const int lane = tid & 63;
    const int wave = tid >> 6;

    // staging: wave w stages 32 A rows + 32 B rows (2 DMA instrs each)
    const int srow0 = wave * 32 + (lane >> 2);
    const int chunk = lane & 3;

    const unsigned short* ag[2];
    #pragma unroll
    for (int j = 0; j < 2; j++) {
        int r = srow0 + j * 16;
        int slot = seg + m0 + r;
        if (slot >= NSLOT) slot = NSLOT - 1;   // clamp; write-guarded later
        if (UP) { int t = rowid[slot]; ag[j] = A + (size_t)t * DDIM + kbase + chunk * 8; }
        else    { ag[j] = A + (size_t)slot * FDIM + kbase + chunk * 8; }
    }
    const unsigned short* bg[2];
    #pragma unroll
    for (int j = 0; j < 2; j++) {
        int r = srow0 + j * 16;
        bg[j] = Wb + ((size_t)e * NOUT + n0 + r) * KDIM + kbase + chunk * 8;
    }
    unsigned short* asl[2];
    unsigned short* bsl[2];
    #pragma unroll
    for (int j = 0; j < 2; j++) {
        asl[j] = &As[(wave * 32 + j * 16) * LDT] + lane * 8;
        bsl[j] = &Bs[(wave * 32 + j * 16) * LDT] + lane * 8;
    }

    const int wm = (wave >> 1) * 64;
    const int wn = (wave & 1) * 64;
    const int frow = lane & 15;
    const int quad = lane >> 4;

    floatx4 acc[4][4];
    #pragma unroll
    for (int i = 0; i < 4; i++)
        #pragma unroll
        for (int j = 0; j < 4; j++)
            acc[i][j] = (floatx4){0.f, 0.f, 0.f, 0.f};

    for (int k0 = 0; k0 < KLEN; k0 += BK) {
        __syncthreads();                 // WAR: previous iter's ds_reads done
        gl2lds16(ag[0], asl[0]);
        gl2lds16(ag[1], asl[1]);
        gl2lds16(bg[0], bsl[0]);
        gl2lds16(bg[1], bsl[1]);
        ag[0] += BK; ag[1] += BK; bg[0] += BK; bg[1] += BK;
        __syncthreads();                 // drain DMA

        bf16x8 av[4], bv[4];
        #pragma unroll
        for (int i = 0; i < 4; i++)
            av[i] = *(const bf16x8*)&As[(wm + i * 16 + frow) * LDT + quad * 8];
        #pragma unroll
        for (int i = 0; i < 4; i++)
            bv[i] = *(const bf16x8*)&Bs[(wn + i * 16 + frow) * LDT + quad * 8];
        #pragma unroll
        for (int mt = 0; mt < 4; mt++)
            #pragma unroll
            for (int nt = 0; nt < 4; nt++)
                acc[mt][nt] = __builtin_amdgcn_mfma_f32_16x16x32_bf16(av[mt], bv[nt], acc[mt][nt], 0, 0, 0);
    }

    // epilogue: C/D layout col=lane&15, row=quad*4+reg (m89/m91-verified)
    #pragma unroll
    for (int mt = 0; mt < 4; mt++) {
        #pragma unroll
        for (int r = 0; r < 4; r++) {
            int mloc = m0 + wm + mt * 16 + quad * 4 + r;
            if (mloc >= cnt) continue;   // write-guard
            int slot = seg + mloc;
            if (UP) {
                #pragma unroll
                for (int nt = 0; nt < 4; nt++) {
                    int n = n0 + wn + nt * 16 + frow;
                    float v = acc[mt][nt][r];
                    float g = 0.5f * v * (1.0f + erff(v * 0.70710678118654752f)); // exact gelu
                    Hout[(size_t)slot * FDIM + n] = f2bf(g);
                }
            } else {
                float gw = gate[slot];
                #pragma unroll
                for (int nt = 0; nt < 4; nt++) {
                    int n = n0 + wn + nt * 16 + frow;
                    Y[((size_t)ks * NSLOT + slot) * DDIM + n] = gw * acc[mt][nt][r];
                }
            }
        }
    }
}

// ---------------- combine: out[t] = sum over ks slabs of Y[slot0]+Y[slot1] ----------------
__global__ void combine_kernel(const float* __restrict__ Y, const int* __restrict__ tok2slot,
                               float* __restrict__ out) {
    int idx = blockIdx.x * 256 + threadIdx.x;
    int t = idx >> 8;
    int c = (idx & 255) * 4;
    int s0 = tok2slot[t * 2], s1 = tok2slot[t * 2 + 1];
    float4 r = make_float4(0.f, 0.f, 0.f, 0.f);
    #pragma unroll
    for (int ks = 0; ks < KSPLIT; ks++) {
        float4 a = *(const float4*)(Y + ((size_t)ks * NSLOT + s0) * DDIM + c);
        float4 b = *(const float4*)(Y + ((size_t)ks * NSLOT + s1) * DDIM + c);
        r.x += a.x + b.x; r.y += a.y + b.y; r.z += a.z + b.z; r.w += a.w + b.w;
    }
    *(float4*)(out + (size_t)t * DDIM + c) = r;
}

extern "C" void kernel_launch(void* const* d_in, const int* in_sizes, int n_in,
                              void* d_out, int out_size, void* d_ws, size_t ws_size,
                              hipStream_t stream) {
    const float* x  = (const float*)d_in[0];
    const float* Wr = (const float*)d_in[1];
    const float* W1 = (const float*)d_in[2];
    const float* W2 = (const float*)d_in[3];
    float* out = (float*)d_out;

    char* ws = (char*)d_ws;
    size_t off = 0;
    auto alloc = [&](size_t bytes) -> char* {
        char* p = ws + off;
        off = (off + bytes + 255) & ~(size_t)255;
        return p;
    };
    unsigned short* xb   = (unsigned short*)alloc((size_t)N_TOK * DDIM * 2);
    unsigned short* H    = (unsigned short*)alloc((size_t)NSLOT * FDIM * 2);
    float* Yb      = (float*)alloc((size_t)KSPLIT * NSLOT * DDIM * 4);
    int*   rowid   = (int*)alloc(NSLOT * 4);
    float* gatew   = (float*)alloc(NSLOT * 4);
    int*   te      = (int*)alloc(NSLOT * 4);
    float* tw      = (float*)alloc(NSLOT * 4);
    int*   t2s     = (int*)alloc(NSLOT * 4);
    int*   counts  = (int*)alloc(64);
    int*   offsets = (int*)alloc(64);
    int*   tile_em = (int*)alloc(MAXT * 4);
    int*   ntile   = (int*)alloc(64);
    unsigned short* w1b = (unsigned short*)alloc((size_t)NEXP * FDIM * DDIM * 2);
    unsigned short* w2b = (unsigned short*)alloc((size_t)NEXP * DDIM * FDIM * 2);
    (void)ws_size;

    castW_kernel<<<2 * NEXP * FDIM * DDIM / 4 / 256, 256, 0, stream>>>(W1, W2, w1b, w2b, counts);
    router_kernel<<<N_TOK / 4, 256, 0, stream>>>(x, Wr, xb, te, tw, counts);
    scan_scatter_kernel<<<1, 256, 0, stream>>>(counts, te, tw, offsets, tile_em, ntile,
                                               rowid, gatew, t2s);
    ffn_gemm<true ><<<NN_UP * MAXT, 256, 0, stream>>>(xb, w1b, H, Yb, rowid, gatew,
                                                      offsets, tile_em, ntile);
    ffn_gemm<false><<<NN_DN * MAXT * KSPLIT, 256, 0, stream>>>(H, w2b, H, Yb, rowid, gatew,
                                                               offsets, tile_em, ntile);
    combine_kernel<<<N_TOK, 256, 0, stream>>>(Yb, t2s, out);
}